// Round 12
// baseline (265.251 us; speedup 1.0000x reference)
//
#include <hip/hip_runtime.h>
#include <cmath>

#define EPSF 1e-7f

constexpr int B_ = 4, S_ = 1024, E_ = 1024, H_ = 16, D_ = 64;
constexpr int BS_ = B_ * S_;   // 4096 rows per matrix

typedef __attribute__((ext_vector_type(8))) short bf16x8;
typedef __attribute__((ext_vector_type(4))) float f32x4;

__device__ inline unsigned int fbits(float f) { union { float f; unsigned int u; } x; x.f = f; return x.u; }
__device__ inline float ubits(unsigned int u) { union { unsigned int u; float f; } x; x.u = u; return x.f; }

__device__ inline unsigned short f2bf(float f) {
  unsigned int u = fbits(f);
  unsigned int r = u + 0x7fffu + ((u >> 16) & 1u);   // RNE
  return (unsigned short)(r >> 16);
}
__device__ inline float bf2f(unsigned short h) { return ubits(((unsigned int)h) << 16); }
__device__ inline float fastrcp(float x) { return __builtin_amdgcn_rcpf(x); }

__device__ inline unsigned int packhi(float a, float b) {
  return (fbits(a) >> 16) | (fbits(b) & 0xFFFF0000u);
}
__device__ inline unsigned int packlo(float a, float b) {
  float la = a - ubits(fbits(a) & 0xFFFF0000u);
  float lb = b - ubits(fbits(b) & 0xFFFF0000u);
  return (fbits(la) >> 16) | (fbits(lb) & 0xFFFF0000u);
}

// async global -> LDS DMA, 16B/lane; LDS dest = wave-uniform base + lane*16
__device__ __forceinline__ void async_ld16(const unsigned short* g, unsigned short* l) {
  __builtin_amdgcn_global_load_lds(
      (const __attribute__((address_space(1))) unsigned int*)g,
      (__attribute__((address_space(3))) unsigned int*)l, 16, 0, 0);
}

// ---------------- kernel 1: x -> RNE bf16 + per-row lambda (fused) ----------------
__global__ __launch_bounds__(256) void xsplit_kernel(
    const float* __restrict__ xq, const float* __restrict__ xk,
    const float* __restrict__ xv, unsigned short* __restrict__ Xbf,
    float* __restrict__ lamRow) {
  const int row = blockIdx.x;                 // 0 .. 3*BS-1
  const float* x = (row < BS_) ? xq : (row < 2 * BS_ ? xk : xv);
  const int r = row & (BS_ - 1);
  const int tid = threadIdx.x;
  float4 v = ((const float4*)(x + (size_t)r * E_))[tid];
  float s = v.x * v.x + v.y * v.y + v.z * v.z + v.w * v.w;
  #pragma unroll
  for (int m = 1; m < 64; m <<= 1) s += __shfl_xor(s, m, 64);
  __shared__ float red[4];
  if ((tid & 63) == 0) red[tid >> 6] = s;
  __syncthreads();
  s = red[0] + red[1] + red[2] + red[3];
  uint2 p;
  p.x = (unsigned int)f2bf(v.x) | ((unsigned int)f2bf(v.y) << 16);
  p.y = (unsigned int)f2bf(v.z) | ((unsigned int)f2bf(v.w) << 16);
  ((uint2*)(Xbf + (size_t)row * E_))[tid] = p;
  if (tid == 0) lamRow[row] = 2.0f / fmaxf(1.0f - s, EPSF);
}

// ---------------- kernel 2: transpose + hi/lo split of z + partial column sums ----------------
__global__ __launch_bounds__(256) void zsplit_kernel(
    const float* __restrict__ zq, const float* __restrict__ zk, const float* __restrict__ zv,
    unsigned short* __restrict__ BhiT, unsigned short* __restrict__ BloT,
    float* __restrict__ Zpart) {
  const int mat = blockIdx.z;
  const float* z = mat == 0 ? zq : (mat == 1 ? zk : zv);
  const int k0 = blockIdx.y * 64, n0 = blockIdx.x * 64;
  __shared__ float t[64][65];
  __shared__ float sred[64][4];
  const int tid = threadIdx.x;
  {
    int kr = tid >> 4, nc = (tid & 15) * 4;
    #pragma unroll
    for (int i = 0; i < 4; i++) {
      float4 vv = *(const float4*)(z + (size_t)(k0 + kr + i * 16) * E_ + n0 + nc);
      t[kr + i * 16][nc + 0] = vv.x;
      t[kr + i * 16][nc + 1] = vv.y;
      t[kr + i * 16][nc + 2] = vv.z;
      t[kr + i * 16][nc + 3] = vv.w;
    }
  }
  __syncthreads();
  int nr = tid >> 2, kc = (tid & 3) * 16;
  unsigned int ph[8], pl[8];
  float ss = 0.f;
  #pragma unroll
  for (int p = 0; p < 8; p++) {
    float x0 = t[kc + 2 * p][nr], x1 = t[kc + 2 * p + 1][nr];
    ph[p] = packhi(x0, x1);
    pl[p] = packlo(x0, x1);
    ss += x0 * x0 + x1 * x1;
  }
  size_t off = (size_t)mat * E_ * E_ + (size_t)(n0 + nr) * E_ + k0 + kc;
  uint4* dh = (uint4*)(BhiT + off);
  uint4* dl = (uint4*)(BloT + off);
  dh[0] = make_uint4(ph[0], ph[1], ph[2], ph[3]);
  dh[1] = make_uint4(ph[4], ph[5], ph[6], ph[7]);
  dl[0] = make_uint4(pl[0], pl[1], pl[2], pl[3]);
  dl[1] = make_uint4(pl[4], pl[5], pl[6], pl[7]);
  sred[nr][tid & 3] = ss;
  __syncthreads();
  if (tid < 64) {
    float v = sred[tid][0] + sred[tid][1] + sred[tid][2] + sred[tid][3];
    Zpart[(size_t)(mat * 16 + blockIdx.y) * E_ + n0 + tid] = v;
  }
}

// ---------------- kernel 2b: finalize zn / cosh / sinh ----------------
__global__ __launch_bounds__(256) void zstat_final_kernel(
    const float* __restrict__ Zpart,
    const float* __restrict__ bq, const float* __restrict__ bk, const float* __restrict__ bv,
    float* __restrict__ znA, float* __restrict__ chA, float* __restrict__ shA) {
  const int idx = blockIdx.x * 256 + threadIdx.x;   // 0..3071
  const int mat = idx >> 10, col = idx & 1023;
  const float* bb = mat == 0 ? bq : (mat == 1 ? bk : bv);
  float s = 0.f;
  #pragma unroll
  for (int ky = 0; ky < 16; ky++)
    s += Zpart[(size_t)(mat * 16 + ky) * E_ + col];
  float n = fmaxf(sqrtf(s), 1e-15f);
  znA[idx] = n;
  float rb = bb[col];
  chA[idx] = coshf(2.f * rb);
  shA[idx] = sinhf(2.f * rb);
}

// ---------------- kernel 3: 2-term bf16 MFMA GEMM (A*Bhi + A*Blo), async DMA staging ----------------
__global__ __launch_bounds__(256, 3) void hlinear_mfma_kernel(
    const unsigned short* __restrict__ Xbf,
    const unsigned short* __restrict__ BhiT, const unsigned short* __restrict__ BloT,
    const float* __restrict__ lamRow, const float* __restrict__ znA,
    const float* __restrict__ chA, const float* __restrict__ shA,
    unsigned short* __restrict__ Wbf) {
  const int mat = blockIdx.z;
  const unsigned short* xa = Xbf + (size_t)mat * BS_ * E_;
  const unsigned short* bh = BhiT + (size_t)mat * E_ * E_;
  const unsigned short* bl = BloT + (size_t)mat * E_ * E_;
  const int lid = blockIdx.y * 8 + blockIdx.x;   // grid (8, 32, 3)
  const int sqi = lid >> 4, offb = lid & 15;
  const int m0 = ((sqi >> 1) * 4 + (offb & 3)) * 128;
  const int n0 = ((sqi & 1) * 4 + (offb >> 2)) * 128;

  __shared__ unsigned short LDSU[24576];   // 49152 B; epilogue reuses it
  unsigned short* As = LDSU;               // 128 rows x 64 shorts
  unsigned short* Bh = LDSU + 8192;
  unsigned short* Bl = LDSU + 16384;

  const int tid = threadIdx.x;
  const int wid = tid >> 6, lane = tid & 63, quad = lane >> 4, l16 = lane & 15;
  const int wm = (wid >> 1) * 64, wn = (wid & 1) * 64;

  f32x4 acc[4][4];
  #pragma unroll
  for (int i = 0; i < 4; i++)
    #pragma unroll
    for (int j = 0; j < 4; j++) acc[i][j] = (f32x4){0.f, 0.f, 0.f, 0.f};

  const int lrow = lane >> 3;
  const int lcs = ((lane & 7) ^ lrow) * 8;
  const int xsw = (l16 & 7);

  for (int kt = 0; kt < E_ / 64; ++kt) {
    __syncthreads();
    const int kb = kt * 64 + lcs;
    #pragma unroll
    for (int c2 = 0; c2 < 4; c2++) {
      const int c = wid * 4 + c2;
      const int grow = c * 8 + lrow;
      async_ld16(xa + (size_t)(m0 + grow) * E_ + kb, As + c * 512);
      async_ld16(bh + (size_t)(n0 + grow) * E_ + kb, Bh + c * 512);
      async_ld16(bl + (size_t)(n0 + grow) * E_ + kb, Bl + c * 512);
    }
    __syncthreads();
    #pragma unroll
    for (int h = 0; h < 2; h++) {
      bf16x8 a[4];
      #pragma unroll
      for (int mt = 0; mt < 4; mt++) {
        int row = wm + mt * 16 + l16;
        a[mt] = *(const bf16x8*)&As[row * 64 + (((h * 4 + quad) ^ xsw) * 8)];
      }
      #pragma unroll
      for (int nt = 0; nt < 4; nt++) {
        int row = wn + nt * 16 + l16;
        int ro = row * 64 + (((h * 4 + quad) ^ xsw) * 8);
        bf16x8 bhf = *(const bf16x8*)&Bh[ro];
        bf16x8 blf = *(const bf16x8*)&Bl[ro];
        #pragma unroll
        for (int mt = 0; mt < 4; mt++) {
          acc[mt][nt] = __builtin_amdgcn_mfma_f32_16x16x32_bf16(a[mt], bhf, acc[mt][nt], 0, 0, 0);
          acc[mt][nt] = __builtin_amdgcn_mfma_f32_16x16x32_bf16(a[mt], blf, acc[mt][nt], 0, 0, 0);
        }
      }
    }
  }

  const float* lamP = lamRow + mat * BS_;
  float lamv[16];
  #pragma unroll
  for (int mt = 0; mt < 4; mt++)
    #pragma unroll
    for (int r = 0; r < 4; r++)
      lamv[mt * 4 + r] = lamP[m0 + wm + mt * 16 + quad * 4 + r];

  __syncthreads();
  unsigned short* epi = LDSU + wid * 4608;   // 64 rows x 72 shorts
  #pragma unroll
  for (int nt = 0; nt < 4; nt++) {
    int cg = n0 + wn + nt * 16 + l16;
    float zn = znA[mat * E_ + cg];
    float chzn = chA[mat * E_ + cg] / zn;
    float sh = shA[mat * E_ + cg];
    float tzn = 2.f * zn;
    #pragma unroll
    for (int mt = 0; mt < 4; mt++) {
      #pragma unroll
      for (int r = 0; r < 4; r++) {
        float lam = lamv[mt * 4 + r];
        float arg = fmaf(lam * acc[mt][nt][r], chzn, -(lam - 1.f) * sh);
        float sq2 = sqrtf(fmaf(arg, arg, 1.f));
        float v = tzn * __logf(arg + sq2);
        float ev = __expf(v);
        float w = 0.5f * (ev - fastrcp(ev));
        epi[(mt * 16 + quad * 4 + r) * 72 + nt * 16 + l16] = f2bf(w);
      }
    }
  }
  unsigned short* gout = Wbf + (size_t)mat * BS_ * E_ + (size_t)(m0 + wm) * E_ + n0 + wn;
  const int rrow = lane >> 3, seg = lane & 7;
  #pragma unroll
  for (int i = 0; i < 8; i++) {
    int row = i * 8 + rrow;
    uint4 val = *(const uint4*)&epi[row * 72 + seg * 8];
    *(uint4*)(gout + (size_t)row * E_ + seg * 8) = val;
  }
}

// ---------------- kernel 4: normalize bf16 w -> bf16 P + per-head squared norms ----------------
__global__ __launch_bounds__(256) void normalize_kernel(
    const unsigned short* __restrict__ Wbf, unsigned short* __restrict__ Pbf,
    float* __restrict__ HN) {
  const unsigned short* w = Wbf + (size_t)blockIdx.x * E_;
  int tid = threadIdx.x;
  uint2 wv = ((const uint2*)w)[tid];   // 4 bf16
  float w0 = bf2f((unsigned short)(wv.x & 0xFFFF));
  float w1 = bf2f((unsigned short)(wv.x >> 16));
  float w2 = bf2f((unsigned short)(wv.y & 0xFFFF));
  float w3 = bf2f((unsigned short)(wv.y >> 16));
  float s = w0 * w0 + w1 * w1 + w2 * w2 + w3 * w3;
  #pragma unroll
  for (int m = 1; m < 64; m <<= 1) s += __shfl_xor(s, m, 64);
  __shared__ float red[4];
  if ((tid & 63) == 0) red[tid >> 6] = s;
  __syncthreads();
  s = red[0] + red[1] + red[2] + red[3];
  float t = 1.f / (1.f + sqrtf(1.f + s));
  unsigned short p0 = f2bf(w0 * t), p1 = f2bf(w1 * t), p2 = f2bf(w2 * t), p3 = f2bf(w3 * t);
  uint2 pk;
  pk.x = (unsigned int)p0 | ((unsigned int)p1 << 16);
  pk.y = (unsigned int)p2 | ((unsigned int)p3 << 16);
  ((uint2*)(Pbf + (size_t)blockIdx.x * E_))[tid] = pk;
  float r0 = bf2f(p0), r1 = bf2f(p1), r2 = bf2f(p2), r3 = bf2f(p3);
  float hs = r0 * r0 + r1 * r1 + r2 * r2 + r3 * r3;
  hs += __shfl_xor(hs, 1, 64);
  hs += __shfl_xor(hs, 2, 64);
  hs += __shfl_xor(hs, 4, 64);
  hs += __shfl_xor(hs, 8, 64);
  if ((tid & 15) == 0) HN[(size_t)blockIdx.x * H_ + (tid >> 4)] = hs;
}

// ---------------- kernel 4b: V head-transpose (lambda folded) + per-key transposed stats ----------------
__global__ __launch_bounds__(256) void vtrans_kernel(
    const unsigned short* __restrict__ Pbf, const float* __restrict__ HN,
    unsigned short* __restrict__ VtG, unsigned short* __restrict__ lamMG,
    float* __restrict__ k2T, float* __restrict__ romk2T) {
  const int st = blockIdx.x, h = blockIdx.y, b = blockIdx.z;
  const unsigned short* pv = Pbf + (size_t)2 * BS_ * E_;
  const float* hnk = HN + (size_t)BS_ * H_;
  const float* hnv = HN + (size_t)2 * BS_ * H_;
  __shared__ unsigned short T[64][72];
  __shared__ float lamS[64];
  const int tid = threadIdx.x;
  {
    int lr = tid >> 2, lc = (tid & 3) * 16;
    const uint4* src = (const uint4*)(pv + (size_t)(b * S_ + st * 64 + lr) * E_ + h * 64 + lc);
    *(uint4*)&T[lr][lc] = src[0];
    *(uint4*)&T[lr][lc + 8] = src[1];
  }
  if (tid < 64) {
    float v2 = hnv[(size_t)(b * S_ + st * 64 + tid) * H_ + h];
    float lam = 2.f / fmaxf(1.f - v2, EPSF);
    lamS[tid] = lam;
    size_t sidx = (size_t)(b * H_ + h) * S_ + st * 64 + tid;
    lamMG[sidx] = f2bf(lam - 1.f);
    float k2 = hnk[(size_t)(b * S_ + st * 64 + tid) * H_ + h];
    k2T[sidx] = k2;
    romk2T[sidx] = fastrcp(1.f - k2);
  }
  __syncthreads();
  int d = tid >> 2, sc = (tid & 3) * 16;
  unsigned int o[8];
  #pragma unroll
  for (int i = 0; i < 8; i++) {
    int s0 = sc + 2 * i;
    float f0 = bf2f(T[s0][d]) * lamS[s0];
    float f1 = bf2f(T[s0 + 1][d]) * lamS[s0 + 1];
    o[i] = (unsigned int)f2bf(f0) | ((unsigned int)f2bf(f1) << 16);
  }
  unsigned short* dst = VtG + (size_t)((b * H_ + h) * 64 + d) * S_ + st * 64 + sc;
  ((uint4*)dst)[0] = make_uint4(o[0], o[1], o[2], o[3]);
  ((uint4*)dst)[1] = make_uint4(o[4], o[5], o[6], o[7]);
}

// ---------------- kernel 5: MFMA flash hyperbolic attention (R8 structure + stat preload) ----------------
// S = Q*K^T (K=32), w = A - sqrt(A^2-1) trunc-bf16 into Pw, PV + dnm via K=32 MFMA.
// Whole-sequence per-key stats preloaded to LDS once (coalesced) — nothing global
// sits between the K-loop barriers except the DMA staging itself.
__global__ __launch_bounds__(512) void attention_kernel(
    const unsigned short* __restrict__ Pbf, const float* __restrict__ HN,
    const unsigned short* __restrict__ VtG, const unsigned short* __restrict__ lamMG,
    const float* __restrict__ k2T, const float* __restrict__ romk2T,
    float* __restrict__ TV, float scale) {
  const int qt = blockIdx.x, h = blockIdx.y, b = blockIdx.z;   // grid (8,16,4), 512 thr
  const unsigned short* pq = Pbf;
  const unsigned short* pk = Pbf + (size_t)BS_ * E_;
  const float* hnq = HN;

  const int tid = threadIdx.x;
  const int wid = tid >> 6, lane = tid & 63;
  const int quad = lane >> 4, l16 = lane & 15;

  __shared__ __align__(16) unsigned short Kl[4096];   // 64 keys x 64 dims, chunk-xor swizzled
  __shared__ __align__(16) unsigned short Vl[4096];   // 64 dims x 64 keys, chunk-xor swizzled
  __shared__ __align__(16) unsigned short Pw[8][16][72];
  __shared__ __align__(16) float k2L[1024];
  __shared__ __align__(16) float rkL[1024];
  __shared__ __align__(16) unsigned short lamL[1024];

  const size_t bhS = (size_t)(b * H_ + h) * S_;
  // preload per-key stats for the whole sequence (coalesced, once)
  ((float2*)k2L)[tid] = ((const float2*)(k2T + bhS))[tid];
  ((float2*)rkL)[tid] = ((const float2*)(romk2T + bhS))[tid];
  ((unsigned int*)lamL)[tid] = ((const unsigned int*)(lamMG + bhS))[tid];

  const int qrow0 = qt * 128 + wid * 16;
  const size_t qgrow = ((size_t)(b * S_ + qrow0 + l16)) * E_ + h * 64;
  bf16x8 aq0 = *(const bf16x8*)(pq + qgrow + quad * 8);
  bf16x8 aq1 = *(const bf16x8*)(pq + qgrow + 32 + quad * 8);
  float q2r[4], tromq2[4];
  #pragma unroll
  for (int r2 = 0; r2 < 4; r2++) {
    float q2 = hnq[((size_t)(b * S_ + qrow0 + quad * 4 + r2)) * H_ + h];
    q2r[r2] = q2;
    tromq2[r2] = 2.f * fastrcp(1.f - q2);
  }

  f32x4 accO[4];
  #pragma unroll
  for (int dt = 0; dt < 4; dt++) accO[dt] = (f32x4){0.f, 0.f, 0.f, 0.f};
  f32x4 accD = (f32x4){0.f, 0.f, 0.f, 0.f};

  const int lr = lane >> 3, cch = lane & 7;
  const int xsw = l16 & 7;
  const unsigned short* kbase = pk + (size_t)(b * S_) * E_ + h * 64;
  const unsigned short* vbase = VtG + bhS * 64;

  for (int kt = 0; kt < S_ / 64; ++kt) {
    __syncthreads();
    {
      const int r = wid * 8 + lr;                    // K: key row / V: dim row (8 waves x 8)
      const int cc = ((cch ^ lr) * 8);               // r&7 == lr
      async_ld16(kbase + (size_t)(kt * 64 + r) * E_ + cc, Kl + wid * 512);
      async_ld16(vbase + (size_t)r * S_ + kt * 64 + cc, Vl + wid * 512);
    }
    __syncthreads();

    // ---- scores: S = Q*K^T MFMA + algebraic weight, trunc-bf16 into Pw ----
    #pragma unroll
    for (int nt = 0; nt < 4; nt++) {
      const int krow = nt * 16 + l16;
      bf16x8 bk0 = *(const bf16x8*)&Kl[krow * 64 + ((quad ^ xsw) * 8)];
      bf16x8 bk1 = *(const bf16x8*)&Kl[krow * 64 + (((4 + quad) ^ xsw) * 8)];
      f32x4 z = (f32x4){0.f, 0.f, 0.f, 0.f};
      f32x4 d0 = __builtin_amdgcn_mfma_f32_16x16x32_bf16(aq0, bk0, z, 0, 0, 0);
      d0 = __builtin_amdgcn_mfma_f32_16x16x32_bf16(aq1, bk1, d0, 0, 0, 0);
      float k2 = k2L[kt * 64 + krow];
      float romk2 = rkL[kt * 64 + krow];
      #pragma unroll
      for (int r2 = 0; r2 < 4; r2++) {
        float diff2 = fmaf(-2.f, d0[r2], q2r[r2] + k2);
        float t = fmaxf(diff2 * (tromq2[r2] * romk2), 1e-6f);
        float A = 1.f + t;
        float w = A - sqrtf(fmaf(A, A, -1.f));
        Pw[wid][quad * 4 + r2][krow] = (unsigned short)(fbits(w) >> 16);
      }
    }
    // ---- PV + dnm via K=32 MFMA (wave-private Pw round-trip) ----
    bf16x8 ap0 = *(const bf16x8*)&Pw[wid][l16][quad * 8];
    bf16x8 ap1 = *(const bf16x8*)&Pw[wid][l16][32 + quad * 8];
    #pragma unroll
    for (int dt = 0; dt < 4; dt++) {
      const int drow = dt * 16 + l16;
      bf16x8 bv0 = *(const bf16x8*)&Vl[drow * 64 + ((quad ^ xsw) * 8)];
      bf16x8 bv1 = *(const bf16x8*)&Vl[drow * 64 + (((4 + quad) ^ xsw) * 8)];
      accO[dt] = __builtin_amdgcn_mfma_f32_16x16x32_bf16(ap0, bv0, accO[dt], 0, 0, 0);
      accO[dt] = __builtin_amdgcn_mfma_f32_16x16x32_bf16(ap1, bv1, accO[dt], 0, 0, 0);
    }
    bf16x8 bl0 = *(const bf16x8*)&lamL[kt * 64 + quad * 8];        // broadcast per quad
    bf16x8 bl1 = *(const bf16x8*)&lamL[kt * 64 + 32 + quad * 8];
    accD = __builtin_amdgcn_mfma_f32_16x16x32_bf16(ap0, bl0, accD, 0, 0, 0);
    accD = __builtin_amdgcn_mfma_f32_16x16x32_bf16(ap1, bl1, accD, 0, 0, 0);
  }

  // ---- finalize: u = num/dnm; midpoint; logmap0*scale ----
  #pragma unroll
  for (int r2 = 0; r2 < 4; r2++) {
    float rdsum = 1.f / accD[r2];                    // dnm >= 1 (lam-1 >= 1)
    float uu[4];
    float su = 0.f;
    #pragma unroll
    for (int dt = 0; dt < 4; dt++) { uu[dt] = accO[dt][r2] * rdsum; su += uu[dt] * uu[dt]; }
    su += __shfl_xor(su, 1, 64);
    su += __shfl_xor(su, 2, 64);
    su += __shfl_xor(su, 4, 64);
    su += __shfl_xor(su, 8, 64);
    float g = 1.f / (1.f + sqrtf(fmaxf(1.f - su, EPSF)));
    float n2 = fmaxf(su * g * g, 1e-15f);
    float n = sqrtf(n2);
    float fac = atanhf(fminf(n, 1.f - 1e-6f)) / n * g * scale;
    size_t orow = ((size_t)(b * S_ + qrow0 + quad * 4 + r2)) * E_ + h * 64 + l16;
    #pragma unroll
    for (int dt = 0; dt < 4; dt++) TV[orow + dt * 16] = fac * uu[dt];
  }
}

// ---------------- kernel 6: expmap0 per full E-row, in-place on d_out ----------------
__global__ __launch_bounds__(256) void expmap_kernel(float* __restrict__ TV) {
  float* w = TV + (size_t)blockIdx.x * E_;
  int tid = threadIdx.x;
  float4 v = ((float4*)w)[tid];
  float s = v.x * v.x + v.y * v.y + v.z * v.z + v.w * v.w;
  #pragma unroll
  for (int m = 1; m < 64; m <<= 1) s += __shfl_xor(s, m, 64);
  __shared__ float red[4];
  if ((tid & 63) == 0) red[tid >> 6] = s;
  __syncthreads();
  s = red[0] + red[1] + red[2] + red[3];
  float n = sqrtf(fmaxf(s, 1e-15f));
  float f = tanhf(n) / n;
  v.x *= f; v.y *= f; v.z *= f; v.w *= f;
  ((float4*)w)[tid] = v;
}

extern "C" void kernel_launch(void* const* d_in, const int* in_sizes, int n_in,
                              void* d_out, int out_size, void* d_ws, size_t ws_size,
                              hipStream_t stream) {
  (void)in_sizes; (void)n_in; (void)out_size; (void)ws_size;
  const float* q  = (const float*)d_in[0];
  const float* k  = (const float*)d_in[1];
  const float* v  = (const float*)d_in[2];
  const float* zq = (const float*)d_in[3];
  const float* bq = (const float*)d_in[4];
  const float* zk = (const float*)d_in[5];
  const float* bk = (const float*)d_in[6];
  const float* zv = (const float*)d_in[7];
  const float* bv = (const float*)d_in[8];

  unsigned short* Wbf = (unsigned short*)d_ws;                       // 3*BS*E bf16 (25.2 MB)
  unsigned short* Pbf = Wbf + (size_t)3 * BS_ * E_;                  // 3*BS*E bf16 (25.2 MB)
  unsigned short* BhiT = Pbf;                                        // aliases Pbf (dead until normalize)
  unsigned short* BloT = Pbf + (size_t)3 * E_ * E_;
  unsigned short* Xbf = Pbf + (size_t)3 * BS_ * E_;                  // 3*BS*E bf16 (25.2 MB)
  float* HN           = (float*)(Xbf + (size_t)3 * BS_ * E_);        // 3*BS*16 fp32
  float* lamRow       = HN + (size_t)3 * BS_ * H_;
  float* znA          = lamRow + 3 * BS_;
  float* chA          = znA + 3 * E_;
  float* shA          = chA + 3 * E_;
  float* Zpart        = shA + 3 * E_;                                // 3*16*1024 fp32 (196 KB)
  unsigned short* VtG = (unsigned short*)(Zpart + 48 * E_);          // B*H*64*S bf16 (8.4 MB)
  unsigned short* lamMG = VtG + (size_t)B_ * H_ * 64 * S_;           // B*H*S bf16 (128 KB)
  float* k2T          = (float*)(lamMG + (size_t)B_ * H_ * S_);      // B*H*S fp32 (256 KB)
  float* romk2T       = k2T + (size_t)B_ * H_ * S_;                  // B*H*S fp32 (256 KB)
  float* out          = (float*)d_out;

  double lb1 = lgamma(E_ / 2.0) + lgamma(0.5) - lgamma(E_ / 2.0 + 0.5);
  double lb2 = lgamma(D_ / 2.0) + lgamma(0.5) - lgamma(D_ / 2.0 + 0.5);
  float scale = (float)exp(lb1 - lb2);

  hipLaunchKernelGGL(xsplit_kernel, dim3(3 * BS_), dim3(256), 0, stream, q, k, v, Xbf, lamRow);
  hipLaunchKernelGGL(zsplit_kernel, dim3(16, 16, 3), dim3(256), 0, stream,
                     zq, zk, zv, BhiT, BloT, Zpart);
  hipLaunchKernelGGL(zstat_final_kernel, dim3(12), dim3(256), 0, stream,
                     Zpart, bq, bk, bv, znA, chA, shA);
  hipLaunchKernelGGL(hlinear_mfma_kernel, dim3(8, 32, 3), dim3(256), 0, stream,
                     Xbf, BhiT, BloT, lamRow, znA, chA, shA, Wbf);
  hipLaunchKernelGGL(normalize_kernel, dim3(3 * BS_), dim3(256), 0, stream, Wbf, Pbf, HN);
  hipLaunchKernelGGL(vtrans_kernel, dim3(16, 16, 4), dim3(256), 0, stream,
                     Pbf, HN, VtG, lamMG, k2T, romk2T);
  hipLaunchKernelGGL(attention_kernel, dim3(8, 16, 4), dim3(512), 0, stream,
                     Pbf, HN, VtG, lamMG, k2T, romk2T, out, scale);
  hipLaunchKernelGGL(expmap_kernel, dim3(BS_), dim3(256), 0, stream, out);
}

// Round 13
// 246.915 us; speedup vs baseline: 1.0743x; 1.0743x over previous
//
#include <hip/hip_runtime.h>
#include <cmath>

#define EPSF 1e-7f

constexpr int B_ = 4, S_ = 1024, E_ = 1024, H_ = 16, D_ = 64;
constexpr int BS_ = B_ * S_;   // 4096 rows per matrix

typedef __attribute__((ext_vector_type(8))) short bf16x8;
typedef __attribute__((ext_vector_type(4))) float f32x4;

__device__ inline unsigned int fbits(float f) { union { float f; unsigned int u; } x; x.f = f; return x.u; }
__device__ inline float ubits(unsigned int u) { union { unsigned int u; float f; } x; x.u = u; return x.f; }

__device__ inline unsigned short f2bf(float f) {
  unsigned int u = fbits(f);
  unsigned int r = u + 0x7fffu + ((u >> 16) & 1u);   // RNE
  return (unsigned short)(r >> 16);
}
__device__ inline float bf2f(unsigned short h) { return ubits(((unsigned int)h) << 16); }
__device__ inline float fastrcp(float x) { return __builtin_amdgcn_rcpf(x); }

// async global -> LDS DMA, 16B/lane; LDS dest = wave-uniform base + lane*16
__device__ __forceinline__ void async_ld16(const unsigned short* g, unsigned short* l) {
  __builtin_amdgcn_global_load_lds(
      (const __attribute__((address_space(1))) unsigned int*)g,
      (__attribute__((address_space(3))) unsigned int*)l, 16, 0, 0);
}

// ---------------- kernel 1: x -> RNE bf16 + per-row lambda (fused) ----------------
__global__ __launch_bounds__(256) void xsplit_kernel(
    const float* __restrict__ xq, const float* __restrict__ xk,
    const float* __restrict__ xv, unsigned short* __restrict__ Xbf,
    float* __restrict__ lamRow) {
  const int row = blockIdx.x;                 // 0 .. 3*BS-1
  const float* x = (row < BS_) ? xq : (row < 2 * BS_ ? xk : xv);
  const int r = row & (BS_ - 1);
  const int tid = threadIdx.x;
  float4 v = ((const float4*)(x + (size_t)r * E_))[tid];
  float s = v.x * v.x + v.y * v.y + v.z * v.z + v.w * v.w;
  #pragma unroll
  for (int m = 1; m < 64; m <<= 1) s += __shfl_xor(s, m, 64);
  __shared__ float red[4];
  if ((tid & 63) == 0) red[tid >> 6] = s;
  __syncthreads();
  s = red[0] + red[1] + red[2] + red[3];
  uint2 p;
  p.x = (unsigned int)f2bf(v.x) | ((unsigned int)f2bf(v.y) << 16);
  p.y = (unsigned int)f2bf(v.z) | ((unsigned int)f2bf(v.w) << 16);
  ((uint2*)(Xbf + (size_t)row * E_))[tid] = p;
  if (tid == 0) lamRow[row] = 2.0f / fmaxf(1.0f - s, EPSF);
}

// ---------------- kernel 2: transpose z -> RNE bf16 BT[n][k] + partial column sums ----------------
__global__ __launch_bounds__(256) void zsplit_kernel(
    const float* __restrict__ zq, const float* __restrict__ zk, const float* __restrict__ zv,
    unsigned short* __restrict__ BhiT, float* __restrict__ Zpart) {
  const int mat = blockIdx.z;
  const float* z = mat == 0 ? zq : (mat == 1 ? zk : zv);
  const int k0 = blockIdx.y * 64, n0 = blockIdx.x * 64;
  __shared__ float t[64][65];
  __shared__ float sred[64][4];
  const int tid = threadIdx.x;
  {
    int kr = tid >> 4, nc = (tid & 15) * 4;
    #pragma unroll
    for (int i = 0; i < 4; i++) {
      float4 vv = *(const float4*)(z + (size_t)(k0 + kr + i * 16) * E_ + n0 + nc);
      t[kr + i * 16][nc + 0] = vv.x;
      t[kr + i * 16][nc + 1] = vv.y;
      t[kr + i * 16][nc + 2] = vv.z;
      t[kr + i * 16][nc + 3] = vv.w;
    }
  }
  __syncthreads();
  int nr = tid >> 2, kc = (tid & 3) * 16;
  unsigned int ph[8];
  float ss = 0.f;
  #pragma unroll
  for (int p = 0; p < 8; p++) {
    float x0 = t[kc + 2 * p][nr], x1 = t[kc + 2 * p + 1][nr];
    ph[p] = (unsigned int)f2bf(x0) | ((unsigned int)f2bf(x1) << 16);
    ss += x0 * x0 + x1 * x1;
  }
  size_t off = (size_t)mat * E_ * E_ + (size_t)(n0 + nr) * E_ + k0 + kc;
  uint4* dh = (uint4*)(BhiT + off);
  dh[0] = make_uint4(ph[0], ph[1], ph[2], ph[3]);
  dh[1] = make_uint4(ph[4], ph[5], ph[6], ph[7]);
  sred[nr][tid & 3] = ss;
  __syncthreads();
  if (tid < 64) {
    float v = sred[tid][0] + sred[tid][1] + sred[tid][2] + sred[tid][3];
    Zpart[(size_t)(mat * 16 + blockIdx.y) * E_ + n0 + tid] = v;
  }
}

// ---------------- kernel 2b: finalize zn / cosh / sinh ----------------
__global__ __launch_bounds__(256) void zstat_final_kernel(
    const float* __restrict__ Zpart,
    const float* __restrict__ bq, const float* __restrict__ bk, const float* __restrict__ bv,
    float* __restrict__ znA, float* __restrict__ chA, float* __restrict__ shA) {
  const int idx = blockIdx.x * 256 + threadIdx.x;   // 0..3071
  const int mat = idx >> 10, col = idx & 1023;
  const float* bb = mat == 0 ? bq : (mat == 1 ? bk : bv);
  float s = 0.f;
  #pragma unroll
  for (int ky = 0; ky < 16; ky++)
    s += Zpart[(size_t)(mat * 16 + ky) * E_ + col];
  float n = fmaxf(sqrtf(s), 1e-15f);
  znA[idx] = n;
  float rb = bb[col];
  chA[idx] = coshf(2.f * rb);
  shA[idx] = sinhf(2.f * rb);
}

// ---------------- kernel 3: 1-term bf16 MFMA GEMM (RNE A,B), async DMA staging ----------------
__global__ __launch_bounds__(256, 3) void hlinear_mfma_kernel(
    const unsigned short* __restrict__ Xbf,
    const unsigned short* __restrict__ BhiT,
    const float* __restrict__ lamRow, const float* __restrict__ znA,
    const float* __restrict__ chA, const float* __restrict__ shA,
    unsigned short* __restrict__ Wbf) {
  const int mat = blockIdx.z;
  const unsigned short* xa = Xbf + (size_t)mat * BS_ * E_;
  const unsigned short* bh = BhiT + (size_t)mat * E_ * E_;
  const int lid = blockIdx.y * 8 + blockIdx.x;   // grid (8, 32, 3)
  const int sqi = lid >> 4, offb = lid & 15;
  const int m0 = ((sqi >> 1) * 4 + (offb & 3)) * 128;
  const int n0 = ((sqi & 1) * 4 + (offb >> 2)) * 128;

  __shared__ unsigned short LDSU[18432];   // 36864 B; staging (As,Bh) + epilogue reuse
  unsigned short* As = LDSU;               // 128 rows x 64 shorts
  unsigned short* Bh = LDSU + 8192;

  const int tid = threadIdx.x;
  const int wid = tid >> 6, lane = tid & 63, quad = lane >> 4, l16 = lane & 15;
  const int wm = (wid >> 1) * 64, wn = (wid & 1) * 64;

  f32x4 acc[4][4];
  #pragma unroll
  for (int i = 0; i < 4; i++)
    #pragma unroll
    for (int j = 0; j < 4; j++) acc[i][j] = (f32x4){0.f, 0.f, 0.f, 0.f};

  const int lrow = lane >> 3;
  const int lcs = ((lane & 7) ^ lrow) * 8;
  const int xsw = (l16 & 7);

  for (int kt = 0; kt < E_ / 64; ++kt) {
    __syncthreads();
    const int kb = kt * 64 + lcs;
    #pragma unroll
    for (int c2 = 0; c2 < 4; c2++) {
      const int c = wid * 4 + c2;
      const int grow = c * 8 + lrow;
      async_ld16(xa + (size_t)(m0 + grow) * E_ + kb, As + c * 512);
      async_ld16(bh + (size_t)(n0 + grow) * E_ + kb, Bh + c * 512);
    }
    __syncthreads();
    #pragma unroll
    for (int h = 0; h < 2; h++) {
      bf16x8 a[4];
      #pragma unroll
      for (int mt = 0; mt < 4; mt++) {
        int row = wm + mt * 16 + l16;
        a[mt] = *(const bf16x8*)&As[row * 64 + (((h * 4 + quad) ^ xsw) * 8)];
      }
      #pragma unroll
      for (int nt = 0; nt < 4; nt++) {
        int row = wn + nt * 16 + l16;
        bf16x8 bhf = *(const bf16x8*)&Bh[row * 64 + (((h * 4 + quad) ^ xsw) * 8)];
        #pragma unroll
        for (int mt = 0; mt < 4; mt++)
          acc[mt][nt] = __builtin_amdgcn_mfma_f32_16x16x32_bf16(a[mt], bhf, acc[mt][nt], 0, 0, 0);
      }
    }
  }

  const float* lamP = lamRow + mat * BS_;
  float lamv[16];
  #pragma unroll
  for (int mt = 0; mt < 4; mt++)
    #pragma unroll
    for (int r = 0; r < 4; r++)
      lamv[mt * 4 + r] = lamP[m0 + wm + mt * 16 + quad * 4 + r];

  __syncthreads();
  unsigned short* epi = LDSU + wid * 4608;   // 64 rows x 72 shorts
  #pragma unroll
  for (int nt = 0; nt < 4; nt++) {
    int cg = n0 + wn + nt * 16 + l16;
    float zn = znA[mat * E_ + cg];
    float chzn = chA[mat * E_ + cg] / zn;
    float sh = shA[mat * E_ + cg];
    float tzn = 2.f * zn;
    #pragma unroll
    for (int mt = 0; mt < 4; mt++) {
      #pragma unroll
      for (int r = 0; r < 4; r++) {
        float lam = lamv[mt * 4 + r];
        float arg = fmaf(lam * acc[mt][nt][r], chzn, -(lam - 1.f) * sh);
        float sq2 = sqrtf(fmaf(arg, arg, 1.f));
        float v = tzn * __logf(arg + sq2);
        float ev = __expf(v);
        float w = 0.5f * (ev - fastrcp(ev));
        epi[(mt * 16 + quad * 4 + r) * 72 + nt * 16 + l16] = f2bf(w);
      }
    }
  }
  unsigned short* gout = Wbf + (size_t)mat * BS_ * E_ + (size_t)(m0 + wm) * E_ + n0 + wn;
  const int rrow = lane >> 3, seg = lane & 7;
  #pragma unroll
  for (int i = 0; i < 8; i++) {
    int row = i * 8 + rrow;
    uint4 val = *(const uint4*)&epi[row * 72 + seg * 8];
    *(uint4*)(gout + (size_t)row * E_ + seg * 8) = val;
  }
}

// ---------------- kernel 4: normalize bf16 w -> bf16 P + per-head squared norms ----------------
__global__ __launch_bounds__(256) void normalize_kernel(
    const unsigned short* __restrict__ Wbf, unsigned short* __restrict__ Pbf,
    float* __restrict__ HN) {
  const unsigned short* w = Wbf + (size_t)blockIdx.x * E_;
  int tid = threadIdx.x;
  uint2 wv = ((const uint2*)w)[tid];   // 4 bf16
  float w0 = bf2f((unsigned short)(wv.x & 0xFFFF));
  float w1 = bf2f((unsigned short)(wv.x >> 16));
  float w2 = bf2f((unsigned short)(wv.y & 0xFFFF));
  float w3 = bf2f((unsigned short)(wv.y >> 16));
  float s = w0 * w0 + w1 * w1 + w2 * w2 + w3 * w3;
  #pragma unroll
  for (int m = 1; m < 64; m <<= 1) s += __shfl_xor(s, m, 64);
  __shared__ float red[4];
  if ((tid & 63) == 0) red[tid >> 6] = s;
  __syncthreads();
  s = red[0] + red[1] + red[2] + red[3];
  float t = 1.f / (1.f + sqrtf(1.f + s));
  unsigned short p0 = f2bf(w0 * t), p1 = f2bf(w1 * t), p2 = f2bf(w2 * t), p3 = f2bf(w3 * t);
  uint2 pk;
  pk.x = (unsigned int)p0 | ((unsigned int)p1 << 16);
  pk.y = (unsigned int)p2 | ((unsigned int)p3 << 16);
  ((uint2*)(Pbf + (size_t)blockIdx.x * E_))[tid] = pk;
  float r0 = bf2f(p0), r1 = bf2f(p1), r2 = bf2f(p2), r3 = bf2f(p3);
  float hs = r0 * r0 + r1 * r1 + r2 * r2 + r3 * r3;
  hs += __shfl_xor(hs, 1, 64);
  hs += __shfl_xor(hs, 2, 64);
  hs += __shfl_xor(hs, 4, 64);
  hs += __shfl_xor(hs, 8, 64);
  if ((tid & 15) == 0) HN[(size_t)blockIdx.x * H_ + (tid >> 4)] = hs;
}

// ---------------- kernel 4b: scaled K, V head-transpose (lambda folded), per-key aux ----------------
// KsG[bh][key][d] = bf16(c_k * k_d), c = 1/(1-k2).  auxG[bh][key] = {bf16(c), bf16(c*k2)}.
// VtG[bh][d][key] = bf16(lam * v_d).  lamMG[bh][key] = bf16(lam-1).
__global__ __launch_bounds__(256) void vtrans_kernel(
    const unsigned short* __restrict__ Pbf, const float* __restrict__ HN,
    unsigned short* __restrict__ KsG, unsigned short* __restrict__ VtG,
    unsigned short* __restrict__ lamMG, unsigned int* __restrict__ auxG) {
  const int st = blockIdx.x, h = blockIdx.y, b = blockIdx.z;
  const unsigned short* pk = Pbf + (size_t)BS_ * E_;
  const unsigned short* pv = Pbf + (size_t)2 * BS_ * E_;
  const float* hnk = HN + (size_t)BS_ * H_;
  const float* hnv = HN + (size_t)2 * BS_ * H_;
  __shared__ unsigned short T[64][72];
  __shared__ float lamS[64], cS[64];
  const int tid = threadIdx.x;
  const size_t bhS = (size_t)(b * H_ + h) * S_;
  {
    int lr = tid >> 2, lc = (tid & 3) * 16;
    const uint4* src = (const uint4*)(pv + (size_t)(b * S_ + st * 64 + lr) * E_ + h * 64 + lc);
    *(uint4*)&T[lr][lc] = src[0];
    *(uint4*)&T[lr][lc + 8] = src[1];
  }
  if (tid < 64) {
    float v2 = hnv[(size_t)(b * S_ + st * 64 + tid) * H_ + h];
    float lam = 2.f / fmaxf(1.f - v2, EPSF);
    lamS[tid] = lam;
    size_t sidx = bhS + st * 64 + tid;
    lamMG[sidx] = f2bf(lam - 1.f);
    float k2 = hnk[(size_t)(b * S_ + st * 64 + tid) * H_ + h];
    float rc = fastrcp(1.f - k2);
    cS[tid] = rc;
    auxG[sidx] = (unsigned int)f2bf(rc) | ((unsigned int)f2bf(rc * k2) << 16);
  }
  __syncthreads();
  // V^T with lambda folded
  {
    int d = tid >> 2, sc = (tid & 3) * 16;
    unsigned int o[8];
    #pragma unroll
    for (int i = 0; i < 8; i++) {
      int s0 = sc + 2 * i;
      float f0 = bf2f(T[s0][d]) * lamS[s0];
      float f1 = bf2f(T[s0 + 1][d]) * lamS[s0 + 1];
      o[i] = (unsigned int)f2bf(f0) | ((unsigned int)f2bf(f1) << 16);
    }
    unsigned short* dst = VtG + (bhS * 64) + (size_t)d * S_ + st * 64 + sc;
    ((uint4*)dst)[0] = make_uint4(o[0], o[1], o[2], o[3]);
    ((uint4*)dst)[1] = make_uint4(o[4], o[5], o[6], o[7]);
  }
  // scaled K rows (c folded in)
  {
    int lr = tid >> 2, lc = (tid & 3) * 16;
    float c = cS[lr];
    const uint4* src = (const uint4*)(pk + (size_t)(b * S_ + st * 64 + lr) * E_ + h * 64 + lc);
    union { uint4 q; unsigned short s[8]; } i0, i1, o0, o1;
    i0.q = src[0]; i1.q = src[1];
    #pragma unroll
    for (int j = 0; j < 8; j++) {
      o0.s[j] = f2bf(bf2f(i0.s[j]) * c);
      o1.s[j] = f2bf(bf2f(i1.s[j]) * c);
    }
    unsigned short* dst = KsG + (bhS + st * 64 + lr) * 64 + lc;
    ((uint4*)dst)[0] = o0.q;
    ((uint4*)dst)[1] = o1.q;
  }
}

// ---------------- kernel 5: MFMA attention with augmented-dim distance ----------------
// Qaug=[-2a*q, a*q2, a], Kaug=[c*k, c, c*k2]  =>  MFMA dot = t = a*c*diff2 directly.
// Per score: clamp, A=1+t, w = A - sqrt(A^2-1), trunc store. PV + dnm via K=32 MFMA.
__global__ __launch_bounds__(512) void attention_kernel(
    const unsigned short* __restrict__ Pbf, const float* __restrict__ HN,
    const unsigned short* __restrict__ KsG, const unsigned short* __restrict__ VtG,
    const unsigned short* __restrict__ lamMG, const unsigned int* __restrict__ auxG,
    float* __restrict__ TV, float scale) {
  const int qt = blockIdx.x, h = blockIdx.y, b = blockIdx.z;   // grid (8,16,4), 512 thr
  const unsigned short* pq = Pbf;
  const float* hnq = HN;

  const int tid = threadIdx.x;
  const int wid = tid >> 6, lane = tid & 63;
  const int quad = lane >> 4, l16 = lane & 15;

  __shared__ __align__(16) unsigned short Kl[4096];   // 64 keys x 64 dims (scaled), xor-swizzled
  __shared__ __align__(16) unsigned short Vl[4096];   // 64 dims x 64 keys, xor-swizzled
  __shared__ __align__(16) unsigned short Pw[8][16][72];
  __shared__ __align__(16) unsigned short lamL[1024];
  __shared__ __align__(16) unsigned int auxL[1024];

  const size_t bhS = (size_t)(b * H_ + h) * S_;
  ((unsigned int*)lamL)[tid] = ((const unsigned int*)(lamMG + bhS))[tid];
  ((uint2*)auxL)[tid] = ((const uint2*)(auxG + bhS))[tid];

  const int qrow0 = qt * 128 + wid * 16;
  const size_t qgrow = ((size_t)(b * S_ + qrow0 + l16)) * E_ + h * 64;
  bf16x8 aq0r = *(const bf16x8*)(pq + qgrow + quad * 8);
  bf16x8 aq1r = *(const bf16x8*)(pq + qgrow + 32 + quad * 8);
  const float q2l = hnq[((size_t)(b * S_ + qrow0 + l16)) * H_ + h];
  const float al = 2.f * fastrcp(1.f - q2l);
  const float sc2 = -2.f * al;
  bf16x8 aq0, aq1;
  #pragma unroll
  for (int j = 0; j < 8; j++) {
    aq0[j] = (short)f2bf(bf2f((unsigned short)aq0r[j]) * sc2);
    aq1[j] = (short)f2bf(bf2f((unsigned short)aq1r[j]) * sc2);
  }
  const unsigned short ae0 = (quad == 0) ? f2bf(al * q2l) : 0;
  const unsigned short ae1 = (quad == 0) ? f2bf(al) : 0;
  const bf16x8 aex = (bf16x8){(short)ae0, (short)ae1, 0, 0, 0, 0, 0, 0};

  f32x4 accO[4];
  #pragma unroll
  for (int dt = 0; dt < 4; dt++) accO[dt] = (f32x4){0.f, 0.f, 0.f, 0.f};
  f32x4 accD = (f32x4){0.f, 0.f, 0.f, 0.f};

  const int lr = lane >> 3, cch = lane & 7;
  const int xsw = l16 & 7;
  const unsigned short* kbase = KsG + bhS * 64;   // row stride 64
  const unsigned short* vbase = VtG + bhS * 64;

  for (int kt = 0; kt < S_ / 64; ++kt) {
    __syncthreads();
    {
      const int r = wid * 8 + lr;                    // K: key row / V: dim row (8 waves x 8)
      const int cc = ((cch ^ lr) * 8);               // r&7 == lr
      async_ld16(kbase + (size_t)(kt * 64 + r) * 64 + cc, Kl + wid * 512);
      async_ld16(vbase + (size_t)r * S_ + kt * 64 + cc, Vl + wid * 512);
    }
    __syncthreads();

    // ---- scores: t directly from augmented MFMA; w = A - sqrt(A^2-1) ----
    #pragma unroll
    for (int nt = 0; nt < 4; nt++) {
      const int krow = nt * 16 + l16;
      bf16x8 bk0 = *(const bf16x8*)&Kl[krow * 64 + ((quad ^ xsw) * 8)];
      bf16x8 bk1 = *(const bf16x8*)&Kl[krow * 64 + (((4 + quad) ^ xsw) * 8)];
      unsigned int av = (quad == 0) ? auxL[kt * 64 + krow] : 0u;
      bf16x8 bex = (bf16x8){(short)(av & 0xFFFF), (short)(av >> 16), 0, 0, 0, 0, 0, 0};
      f32x4 z = (f32x4){0.f, 0.f, 0.f, 0.f};
      f32x4 st = __builtin_amdgcn_mfma_f32_16x16x32_bf16(aex, bex, z, 0, 0, 0);
      st = __builtin_amdgcn_mfma_f32_16x16x32_bf16(aq0, bk0, st, 0, 0, 0);
      st = __builtin_amdgcn_mfma_f32_16x16x32_bf16(aq1, bk1, st, 0, 0, 0);
      #pragma unroll
      for (int r2 = 0; r2 < 4; r2++) {
        float t = fmaxf(st[r2], 1e-6f);
        float A = 1.f + t;
        float w = A - sqrtf(fmaf(A, A, -1.f));
        Pw[wid][quad * 4 + r2][krow] = (unsigned short)(fbits(w) >> 16);
      }
    }
    // ---- PV + dnm via K=32 MFMA (wave-private Pw round-trip) ----
    bf16x8 ap0 = *(const bf16x8*)&Pw[wid][l16][quad * 8];
    bf16x8 ap1 = *(const bf16x8*)&Pw[wid][l16][32 + quad * 8];
    #pragma unroll
    for (int dt = 0; dt < 4; dt++) {
      const int drow = dt * 16 + l16;
      bf16x8 bv0 = *(const bf16x8*)&Vl[drow * 64 + ((quad ^ xsw) * 8)];
      bf16x8 bv1 = *(const bf16x8*)&Vl[drow * 64 + (((4 + quad) ^ xsw) * 8)];
      accO[dt] = __builtin_amdgcn_mfma_f32_16x16x32_bf16(ap0, bv0, accO[dt], 0, 0, 0);
      accO[dt] = __builtin_amdgcn_mfma_f32_16x16x32_bf16(ap1, bv1, accO[dt], 0, 0, 0);
    }
    bf16x8 bl0 = *(const bf16x8*)&lamL[kt * 64 + quad * 8];        // broadcast per quad
    bf16x8 bl1 = *(const bf16x8*)&lamL[kt * 64 + 32 + quad * 8];
    accD = __builtin_amdgcn_mfma_f32_16x16x32_bf16(ap0, bl0, accD, 0, 0, 0);
    accD = __builtin_amdgcn_mfma_f32_16x16x32_bf16(ap1, bl1, accD, 0, 0, 0);
  }

  // ---- finalize: u = num/dnm; midpoint; logmap0*scale ----
  #pragma unroll
  for (int r2 = 0; r2 < 4; r2++) {
    float rdsum = 1.f / accD[r2];                    // dnm >= 1 (lam-1 >= 1)
    float uu[4];
    float su = 0.f;
    #pragma unroll
    for (int dt = 0; dt < 4; dt++) { uu[dt] = accO[dt][r2] * rdsum; su += uu[dt] * uu[dt]; }
    su += __shfl_xor(su, 1, 64);
    su += __shfl_xor(su, 2, 64);
    su += __shfl_xor(su, 4, 64);
    su += __shfl_xor(su, 8, 64);
    float g = 1.f / (1.f + sqrtf(fmaxf(1.f - su, EPSF)));
    float n2 = fmaxf(su * g * g, 1e-15f);
    float n = sqrtf(n2);
    float fac = atanhf(fminf(n, 1.f - 1e-6f)) / n * g * scale;
    size_t orow = ((size_t)(b * S_ + qrow0 + quad * 4 + r2)) * E_ + h * 64 + l16;
    #pragma unroll
    for (int dt = 0; dt < 4; dt++) TV[orow + dt * 16] = fac * uu[dt];
  }
}

// ---------------- kernel 6: expmap0 per full E-row, in-place on d_out ----------------
__global__ __launch_bounds__(256) void expmap_kernel(float* __restrict__ TV) {
  float* w = TV + (size_t)blockIdx.x * E_;
  int tid = threadIdx.x;
  float4 v = ((float4*)w)[tid];
  float s = v.x * v.x + v.y * v.y + v.z * v.z + v.w * v.w;
  #pragma unroll
  for (int m = 1; m < 64; m <<= 1) s += __shfl_xor(s, m, 64);
  __shared__ float red[4];
  if ((tid & 63) == 0) red[tid >> 6] = s;
  __syncthreads();
  s = red[0] + red[1] + red[2] + red[3];
  float n = sqrtf(fmaxf(s, 1e-15f));
  float f = tanhf(n) / n;
  v.x *= f; v.y *= f; v.z *= f; v.w *= f;
  ((float4*)w)[tid] = v;
}

extern "C" void kernel_launch(void* const* d_in, const int* in_sizes, int n_in,
                              void* d_out, int out_size, void* d_ws, size_t ws_size,
                              hipStream_t stream) {
  (void)in_sizes; (void)n_in; (void)out_size; (void)ws_size;
  const float* q  = (const float*)d_in[0];
  const float* k  = (const float*)d_in[1];
  const float* v  = (const float*)d_in[2];
  const float* zq = (const float*)d_in[3];
  const float* bq = (const float*)d_in[4];
  const float* zk = (const float*)d_in[5];
  const float* bk = (const float*)d_in[6];
  const float* zv = (const float*)d_in[7];
  const float* bv = (const float*)d_in[8];

  unsigned short* Wbf = (unsigned short*)d_ws;                       // 3*BS*E bf16 (25.2 MB)
  unsigned short* Pbf = Wbf + (size_t)3 * BS_ * E_;                  // 3*BS*E bf16 (25.2 MB)
  unsigned short* BhiT = Pbf;                                        // aliases Pbf (dead until normalize)
  unsigned short* Xbf = Pbf + (size_t)3 * BS_ * E_;                  // 3*BS*E bf16 (25.2 MB)
  float* HN           = (float*)(Xbf + (size_t)3 * BS_ * E_);        // 3*BS*16 fp32
  float* lamRow       = HN + (size_t)3 * BS_ * H_;
  float* znA          = lamRow + 3 * BS_;
  float* chA          = znA + 3 * E_;
  float* shA          = chA + 3 * E_;
  float* Zpart        = shA + 3 * E_;                                // 3*16*1024 fp32 (196 KB)
  unsigned short* VtG = (unsigned short*)(Zpart + 48 * E_);          // B*H*64*S bf16 (8.4 MB)
  unsigned short* KsG = VtG + (size_t)B_ * H_ * 64 * S_;             // B*H*S*64 bf16 (8.4 MB)
  unsigned short* lamMG = KsG + (size_t)B_ * H_ * S_ * 64;           // B*H*S bf16 (128 KB)
  unsigned int* auxG  = (unsigned int*)(lamMG + (size_t)B_ * H_ * S_); // B*H*S uint (256 KB)
  float* out          = (float*)d_out;

  double lb1 = lgamma(E_ / 2.0) + lgamma(0.5) - lgamma(E_ / 2.0 + 0.5);
  double lb2 = lgamma(D_ / 2.0) + lgamma(0.5) - lgamma(D_ / 2.0 + 0.5);
  float scale = (float)exp(lb1 - lb2);

  hipLaunchKernelGGL(xsplit_kernel, dim3(3 * BS_), dim3(256), 0, stream, q, k, v, Xbf, lamRow);
  hipLaunchKernelGGL(zsplit_kernel, dim3(16, 16, 3), dim3(256), 0, stream,
                     zq, zk, zv, BhiT, Zpart);
  hipLaunchKernelGGL(zstat_final_kernel, dim3(12), dim3(256), 0, stream,
                     Zpart, bq, bk, bv, znA, chA, shA);
  hipLaunchKernelGGL(hlinear_mfma_kernel, dim3(8, 32, 3), dim3(256), 0, stream,
                     Xbf, BhiT, lamRow, znA, chA, shA, Wbf);
  hipLaunchKernelGGL(normalize_kernel, dim3(3 * BS_), dim3(256), 0, stream, Wbf, Pbf, HN);
  hipLaunchKernelGGL(vtrans_kernel, dim3(16, 16, 4), dim3(256), 0, stream,
                     Pbf, HN, KsG, VtG, lamMG, auxG);
  hipLaunchKernelGGL(attention_kernel, dim3(8, 16, 4), dim3(512), 0, stream,
                     Pbf, HN, KsG, VtG, lamMG, auxG, out, scale);
  hipLaunchKernelGGL(expmap_kernel, dim3(BS_), dim3(256), 0, stream, out);
}